// Round 1
// baseline (228.159 us; speedup 1.0000x reference)
//
#include <hip/hip_runtime.h>
#include <hip/hip_bf16.h>
#include <math.h>

// Problem constants
#define B_     32
#define DM_    4096
#define H_     32
#define HKV_   8
#define G_     4
#define HD_    128
#define KVLEN_ 2048
#define PBLK_  256
#define NBPS_  8
#define NQKV_  6144   // 4096 q + 1024 k + 1024 v
#define KSPLIT_ 16
#define KC_    256    // 4096 / KSPLIT

// ---------------------------------------------------------------------------
// Kernel 1: fused QKV projection, split-K partials.
// grid = 24 n-tiles * 16 k-splits = 384 blocks, 256 threads.
// Each thread: one output column n, all 32 rows, K-chunk of 256.
// ---------------------------------------------------------------------------
__global__ __launch_bounds__(256) void qkv_gemm(
    const float* __restrict__ seqs, const float* __restrict__ Wq,
    const float* __restrict__ Wk, const float* __restrict__ Wv,
    float* __restrict__ P1) {
  const int tid = threadIdx.x;
  const int nid = blockIdx.x % 24;
  const int kid = blockIdx.x / 24;
  const int k0 = kid * KC_;

  __shared__ __align__(16) float sT[KC_ * 36];  // [kk][m], pad 36 for alignment
  #pragma unroll
  for (int m = 0; m < 32; ++m)
    sT[tid * 36 + m] = seqs[m * DM_ + k0 + tid];
  __syncthreads();

  const int n = nid * 256 + tid;
  const float* W; int col, ldw;
  if (nid < 16)      { W = Wq; col = n;        ldw = 4096; }
  else if (nid < 20) { W = Wk; col = n - 4096; ldw = 1024; }
  else               { W = Wv; col = n - 5120; ldw = 1024; }

  float acc[32];
  #pragma unroll
  for (int m = 0; m < 32; ++m) acc[m] = 0.f;

  const float* wp = W + (size_t)k0 * ldw + col;
  #pragma unroll 4
  for (int kk = 0; kk < KC_; ++kk) {
    float w = wp[(size_t)kk * ldw];
    const float4* s4 = (const float4*)&sT[kk * 36];
    #pragma unroll
    for (int mq = 0; mq < 8; ++mq) {
      float4 a = s4[mq];
      acc[mq * 4 + 0] = fmaf(a.x, w, acc[mq * 4 + 0]);
      acc[mq * 4 + 1] = fmaf(a.y, w, acc[mq * 4 + 1]);
      acc[mq * 4 + 2] = fmaf(a.z, w, acc[mq * 4 + 2]);
      acc[mq * 4 + 3] = fmaf(a.w, w, acc[mq * 4 + 3]);
    }
  }
  float* o = P1 + (size_t)kid * 32 * NQKV_ + n;
  #pragma unroll
  for (int m = 0; m < 32; ++m) o[(size_t)m * NQKV_] = acc[m];
}

// ---------------------------------------------------------------------------
// Kernel 2: reduce split-K partials, RMSNorm (q,k), RoPE (q,k).
// grid = 32 batches * 48 heads (32 q + 8 k + 8 v), 128 threads = HD.
// ---------------------------------------------------------------------------
__global__ __launch_bounds__(128) void reduce_norm_rope(
    const float* __restrict__ P1, const float* __restrict__ qn_w,
    const float* __restrict__ kn_w, const int* __restrict__ input_pos,
    float* __restrict__ qf, float* __restrict__ knew, float* __restrict__ vnew) {
  const int b = blockIdx.x / 48;
  const int hh = blockIdx.x % 48;
  const int tid = threadIdx.x;

  int col0, kind;  // 0=q,1=k,2=v
  if (hh < 32)      { kind = 0; col0 = hh * 128; }
  else if (hh < 40) { kind = 1; col0 = 4096 + (hh - 32) * 128; }
  else              { kind = 2; col0 = 5120 + (hh - 40) * 128; }

  float x = 0.f;
  const float* p = P1 + (size_t)b * NQKV_ + col0 + tid;
  #pragma unroll
  for (int s = 0; s < KSPLIT_; ++s) x += p[(size_t)s * 32 * NQKV_];

  if (kind == 2) {
    vnew[(size_t)b * 1024 + (hh - 40) * 128 + tid] = x;
    return;
  }

  __shared__ float lds[128];
  __shared__ float wred[2];
  // rmsnorm
  float ss = x * x;
  #pragma unroll
  for (int off = 32; off > 0; off >>= 1) ss += __shfl_down(ss, off);
  if ((tid & 63) == 0) wred[tid >> 6] = ss;
  __syncthreads();
  float tot = wred[0] + wred[1];
  float r = rsqrtf(tot * (1.f / 128.f) + 1e-6f);
  const float* wv = (kind == 0) ? qn_w : kn_w;
  x = x * r * wv[tid];

  lds[tid] = x;
  __syncthreads();

  if (tid < 64) {
    float pos = (float)input_pos[b];
    float inv = powf(10000.f, -(float)tid * (1.f / 64.f));
    float ang = pos * inv;
    float c = cosf(ang), s = sinf(ang);
    float x1 = lds[tid], x2 = lds[tid + 64];
    float o1 = x1 * c - x2 * s;
    float o2 = x2 * c + x1 * s;
    float* dst = (kind == 0) ? (qf + (size_t)b * 4096 + hh * 128)
                             : (knew + (size_t)b * 1024 + (hh - 32) * 128);
    dst[tid] = o1;
    dst[tid + 64] = o2;
  }
}

// ---------------------------------------------------------------------------
// Kernel 3: paged GQA decode attention.
// grid = 256 (b, kv) pairs, 512 threads = 8 waves = 32 groups of 16 lanes.
// Group owns one KV position per iteration; online softmax per group;
// merge groups via shuffles, merge waves via LDS.
// ---------------------------------------------------------------------------
__global__ __launch_bounds__(512) void attn_decode(
    const float* __restrict__ qf, const float* __restrict__ knew,
    const float* __restrict__ vnew, const float* __restrict__ kc,
    const float* __restrict__ vc, const int* __restrict__ block_tables,
    const int* __restrict__ slot_mapping, const int* __restrict__ context_lens,
    float* __restrict__ attn) {
  const int b   = blockIdx.x >> 3;
  const int kv  = blockIdx.x & 7;
  const int tid = threadIdx.x;
  const int lane = tid & 63;
  const int wid  = tid >> 6;       // 0..7
  const int l16  = lane & 15;      // lane in group
  const int gid  = tid >> 4;       // 0..31 group id
  const int d0   = l16 * 8;        // dims owned by this lane

  const int ctx   = context_lens[b];
  const int fslot = slot_mapping[b];
  const int* bt   = block_tables + b * NBPS_;

  const float scale = 0.08838834764831845f;  // 1/sqrt(128)
  float q[4][8];
  #pragma unroll
  for (int g = 0; g < 4; ++g) {
    const float4* qp = (const float4*)(qf + ((size_t)b * H_ + kv * G_ + g) * HD_ + d0);
    float4 a = qp[0], c = qp[1];
    q[g][0] = a.x * scale; q[g][1] = a.y * scale; q[g][2] = a.z * scale; q[g][3] = a.w * scale;
    q[g][4] = c.x * scale; q[g][5] = c.y * scale; q[g][6] = c.z * scale; q[g][7] = c.w * scale;
  }

  float mx[4], ls[4], acc[4][8];
  #pragma unroll
  for (int g = 0; g < 4; ++g) {
    mx[g] = -1e30f; ls[g] = 0.f;
    #pragma unroll
    for (int j = 0; j < 8; ++j) acc[g][j] = 0.f;
  }

  for (int l = gid; l < ctx; l += 32) {
    int page = bt[l >> 8];
    int slot = (page << 8) + (l & 255);
    const float *kp, *vp;
    if (slot == fslot) {
      kp = knew + ((size_t)b * HKV_ + kv) * HD_;
      vp = vnew + ((size_t)b * HKV_ + kv) * HD_;
    } else {
      kp = kc + ((size_t)slot * HKV_ + kv) * HD_;
      vp = vc + ((size_t)slot * HKV_ + kv) * HD_;
    }
    float4 k1 = ((const float4*)(kp + d0))[0];
    float4 k2 = ((const float4*)(kp + d0))[1];
    float4 v1 = ((const float4*)(vp + d0))[0];
    float4 v2 = ((const float4*)(vp + d0))[1];
    float kk[8] = {k1.x, k1.y, k1.z, k1.w, k2.x, k2.y, k2.z, k2.w};
    float vv[8] = {v1.x, v1.y, v1.z, v1.w, v2.x, v2.y, v2.z, v2.w};

    float s[4];
    #pragma unroll
    for (int g = 0; g < 4; ++g) {
      float t = 0.f;
      #pragma unroll
      for (int j = 0; j < 8; ++j) t = fmaf(q[g][j], kk[j], t);
      s[g] = t;
    }
    #pragma unroll
    for (int off = 1; off < 16; off <<= 1) {
      #pragma unroll
      for (int g = 0; g < 4; ++g) s[g] += __shfl_xor(s[g], off);
    }
    #pragma unroll
    for (int g = 0; g < 4; ++g) {
      float nm = fmaxf(mx[g], s[g]);
      float corr = __expf(mx[g] - nm);
      float pw = __expf(s[g] - nm);
      mx[g] = nm;
      ls[g] = ls[g] * corr + pw;
      #pragma unroll
      for (int j = 0; j < 8; ++j) acc[g][j] = fmaf(acc[g][j], corr, pw * vv[j]);
    }
  }

  // merge the 4 groups within each wave (xor over lane bits 4,5)
  #pragma unroll
  for (int off = 16; off < 64; off <<= 1) {
    #pragma unroll
    for (int g = 0; g < 4; ++g) {
      float mo = __shfl_xor(mx[g], off);
      float lo = __shfl_xor(ls[g], off);
      float nm = fmaxf(mx[g], mo);
      float c1 = __expf(mx[g] - nm);
      float c2 = __expf(mo - nm);
      ls[g] = ls[g] * c1 + lo * c2;
      mx[g] = nm;
      #pragma unroll
      for (int j = 0; j < 8; ++j) {
        float ao = __shfl_xor(acc[g][j], off);
        acc[g][j] = acc[g][j] * c1 + ao * c2;
      }
    }
  }

  __shared__ float rm[8][4], rl[8][4];
  __shared__ __align__(16) float ra[8][4][128];
  if (lane < 16) {
    #pragma unroll
    for (int g = 0; g < 4; ++g) {
      #pragma unroll
      for (int j = 0; j < 8; ++j) ra[wid][g][d0 + j] = acc[g][j];
    }
    if (lane == 0) {
      #pragma unroll
      for (int g = 0; g < 4; ++g) { rm[wid][g] = mx[g]; rl[wid][g] = ls[g]; }
    }
  }
  __syncthreads();

  // final merge across 8 waves: 512 threads = 4 heads x 128 dims
  {
    int g = tid >> 7;
    int d = tid & 127;
    float M = -1e30f;
    #pragma unroll
    for (int w = 0; w < 8; ++w) M = fmaxf(M, rm[w][g]);
    float L = 0.f, A = 0.f;
    #pragma unroll
    for (int w = 0; w < 8; ++w) {
      float c = __expf(rm[w][g] - M);
      L += c * rl[w][g];
      A += c * ra[w][g][d];
    }
    attn[((size_t)b * H_ + kv * G_ + g) * HD_ + d] = A / L;
  }
}

// ---------------------------------------------------------------------------
// Kernel 4: output projection, split-K partials (same template as kernel 1).
// grid = 16 n-tiles * 16 k-splits = 256 blocks, 256 threads.
// ---------------------------------------------------------------------------
__global__ __launch_bounds__(256) void oproj_gemm(
    const float* __restrict__ A, const float* __restrict__ Wo,
    float* __restrict__ P2) {
  const int tid = threadIdx.x;
  const int nid = blockIdx.x & 15;
  const int kid = blockIdx.x >> 4;
  const int k0 = kid * KC_;

  __shared__ __align__(16) float sT[KC_ * 36];
  #pragma unroll
  for (int m = 0; m < 32; ++m)
    sT[tid * 36 + m] = A[m * 4096 + k0 + tid];
  __syncthreads();

  const int n = nid * 256 + tid;
  float acc[32];
  #pragma unroll
  for (int m = 0; m < 32; ++m) acc[m] = 0.f;

  const float* wp = Wo + (size_t)k0 * 4096 + n;
  #pragma unroll 4
  for (int kk = 0; kk < KC_; ++kk) {
    float w = wp[(size_t)kk * 4096];
    const float4* s4 = (const float4*)&sT[kk * 36];
    #pragma unroll
    for (int mq = 0; mq < 8; ++mq) {
      float4 a = s4[mq];
      acc[mq * 4 + 0] = fmaf(a.x, w, acc[mq * 4 + 0]);
      acc[mq * 4 + 1] = fmaf(a.y, w, acc[mq * 4 + 1]);
      acc[mq * 4 + 2] = fmaf(a.z, w, acc[mq * 4 + 2]);
      acc[mq * 4 + 3] = fmaf(a.w, w, acc[mq * 4 + 3]);
    }
  }
  float* o = P2 + (size_t)kid * 32 * 4096 + n;
  #pragma unroll
  for (int m = 0; m < 32; ++m) o[(size_t)m * 4096] = acc[m];
}

// ---------------------------------------------------------------------------
// Kernel 5: reduce split-K partials of the output projection -> d_out.
// ---------------------------------------------------------------------------
__global__ __launch_bounds__(256) void oproj_reduce(
    const float* __restrict__ P2, float* __restrict__ out) {
  const int idx = blockIdx.x * 256 + threadIdx.x;  // < 131072
  float s = 0.f;
  #pragma unroll
  for (int t = 0; t < KSPLIT_; ++t) s += P2[(size_t)t * 131072 + idx];
  out[idx] = s;
}

// ---------------------------------------------------------------------------
extern "C" void kernel_launch(void* const* d_in, const int* in_sizes, int n_in,
                              void* d_out, int out_size, void* d_ws, size_t ws_size,
                              hipStream_t stream) {
  const float* seqs = (const float*)d_in[0];
  const float* Wq   = (const float*)d_in[1];
  const float* Wk   = (const float*)d_in[2];
  const float* Wv   = (const float*)d_in[3];
  const float* Wo   = (const float*)d_in[4];
  const float* qn_w = (const float*)d_in[5];
  const float* kn_w = (const float*)d_in[6];
  const float* kc   = (const float*)d_in[7];
  const float* vc   = (const float*)d_in[8];
  const int* input_pos = (const int*)d_in[9];
  const int* slot_map  = (const int*)d_in[10];
  const int* btab      = (const int*)d_in[11];
  const int* ctx       = (const int*)d_in[12];
  float* out = (float*)d_out;

  char* w = (char*)d_ws;
  float* P1   = (float*)(w);                         // 16*32*6144*4 = 12,582,912
  float* qf   = (float*)(w + 12582912);              // 32*4096*4    =    524,288
  float* knew = (float*)(w + 13107200);              // 32*1024*4    =    131,072
  float* vnew = (float*)(w + 13238272);              // 32*1024*4    =    131,072
  float* attn = (float*)(w + 13369344);              // 32*4096*4    =    524,288
  float* P2   = (float*)(w + 13893632);              // 16*32*4096*4 =  8,388,608

  qkv_gemm<<<24 * KSPLIT_, 256, 0, stream>>>(seqs, Wq, Wk, Wv, P1);
  reduce_norm_rope<<<B_ * 48, 128, 0, stream>>>(P1, qn_w, kn_w, input_pos, qf, knew, vnew);
  attn_decode<<<B_ * HKV_, 512, 0, stream>>>(qf, knew, vnew, kc, vc, btab, slot_map, ctx, attn);
  oproj_gemm<<<16 * KSPLIT_, 256, 0, stream>>>(attn, Wo, P2);
  oproj_reduce<<<512, 256, 0, stream>>>(P2, out);
}

// Round 2
// 211.769 us; speedup vs baseline: 1.0774x; 1.0774x over previous
//
#include <hip/hip_runtime.h>
#include <hip/hip_bf16.h>
#include <math.h>

// Problem constants
#define B_     32
#define DM_    4096
#define H_     32
#define HKV_   8
#define G_     4
#define HD_    128
#define KVLEN_ 2048
#define NBPS_  8
#define NQKV_  6144   // 4096 q + 1024 k + 1024 v
#define KSPLIT_ 16
#define KC_    256    // 4096 / KSPLIT
#define ASPLIT_ 16
#define APOS_  128    // positions per attention block (KVLEN_/ASPLIT_)

// ---------------------------------------------------------------------------
// Kernel 1: fused QKV projection, split-K partials, register tiling.
// grid = 24 n-tiles * 16 k-splits = 384 blocks, 256 threads.
// Thread: TM=16 rows (mh half) x TN=2 cols, K-chunk 256.
// Per k: 1 float2 W load + 4 ds_read_b128 (wave-uniform broadcast) + 32 FMA.
// ---------------------------------------------------------------------------
__global__ __launch_bounds__(256) void qkv_gemm(
    const float* __restrict__ seqs, const float* __restrict__ Wq,
    const float* __restrict__ Wk, const float* __restrict__ Wv,
    float* __restrict__ P1) {
  const int tid = threadIdx.x;
  const int nid = blockIdx.x % 24;
  const int kid = blockIdx.x / 24;
  const int k0 = kid * KC_;

  __shared__ __align__(16) float sT[KC_ * 36];  // [kk][m], pad 36 (16B-aligned rows)
  #pragma unroll
  for (int m = 0; m < 32; ++m)
    sT[tid * 36 + m] = seqs[m * DM_ + k0 + tid];
  __syncthreads();

  const int ct = tid & 127;   // column-pair index
  const int mh = tid >> 7;    // row half: 0 -> rows 0..15, 1 -> rows 16..31
  const int n  = nid * 256 + ct * 2;

  const float* W; int col, ldw;
  if (nid < 16)      { W = Wq; col = n;        ldw = 4096; }
  else if (nid < 20) { W = Wk; col = n - 4096; ldw = 1024; }
  else               { W = Wv; col = n - 5120; ldw = 1024; }

  float2 acc[16];
  #pragma unroll
  for (int r = 0; r < 16; ++r) acc[r] = make_float2(0.f, 0.f);

  const float2* wp = (const float2*)(W + (size_t)k0 * ldw + col);
  const int ldw2 = ldw >> 1;

  #pragma unroll 4
  for (int kk = 0; kk < KC_; ++kk) {
    float2 w = wp[(size_t)kk * ldw2];
    const float4* s4 = (const float4*)(sT + kk * 36 + mh * 16);
    #pragma unroll
    for (int rq = 0; rq < 4; ++rq) {
      float4 a = s4[rq];
      acc[rq*4+0].x = fmaf(a.x, w.x, acc[rq*4+0].x);
      acc[rq*4+0].y = fmaf(a.x, w.y, acc[rq*4+0].y);
      acc[rq*4+1].x = fmaf(a.y, w.x, acc[rq*4+1].x);
      acc[rq*4+1].y = fmaf(a.y, w.y, acc[rq*4+1].y);
      acc[rq*4+2].x = fmaf(a.z, w.x, acc[rq*4+2].x);
      acc[rq*4+2].y = fmaf(a.z, w.y, acc[rq*4+2].y);
      acc[rq*4+3].x = fmaf(a.w, w.x, acc[rq*4+3].x);
      acc[rq*4+3].y = fmaf(a.w, w.y, acc[rq*4+3].y);
    }
  }

  float* o = P1 + (size_t)kid * 32 * NQKV_ + n;
  #pragma unroll
  for (int r = 0; r < 16; ++r) {
    int m = mh * 16 + r;
    *(float2*)(o + (size_t)m * NQKV_) = acc[r];
  }
}

// ---------------------------------------------------------------------------
// Kernel 2: reduce split-K partials, RMSNorm (q,k), RoPE (q,k).
// grid = 32 batches * 48 heads (32 q + 8 k + 8 v), 128 threads = HD.
// ---------------------------------------------------------------------------
__global__ __launch_bounds__(128) void reduce_norm_rope(
    const float* __restrict__ P1, const float* __restrict__ qn_w,
    const float* __restrict__ kn_w, const int* __restrict__ input_pos,
    float* __restrict__ qf, float* __restrict__ knew, float* __restrict__ vnew) {
  const int b = blockIdx.x / 48;
  const int hh = blockIdx.x % 48;
  const int tid = threadIdx.x;

  int col0, kind;  // 0=q,1=k,2=v
  if (hh < 32)      { kind = 0; col0 = hh * 128; }
  else if (hh < 40) { kind = 1; col0 = 4096 + (hh - 32) * 128; }
  else              { kind = 2; col0 = 5120 + (hh - 40) * 128; }

  float x = 0.f;
  const float* p = P1 + (size_t)b * NQKV_ + col0 + tid;
  #pragma unroll
  for (int s = 0; s < KSPLIT_; ++s) x += p[(size_t)s * 32 * NQKV_];

  if (kind == 2) {
    vnew[(size_t)b * 1024 + (hh - 40) * 128 + tid] = x;
    return;
  }

  __shared__ float lds[128];
  __shared__ float wred[2];
  float ss = x * x;
  #pragma unroll
  for (int off = 32; off > 0; off >>= 1) ss += __shfl_down(ss, off);
  if ((tid & 63) == 0) wred[tid >> 6] = ss;
  __syncthreads();
  float tot = wred[0] + wred[1];
  float r = rsqrtf(tot * (1.f / 128.f) + 1e-6f);
  const float* wv = (kind == 0) ? qn_w : kn_w;
  x = x * r * wv[tid];

  lds[tid] = x;
  __syncthreads();

  if (tid < 64) {
    float pos = (float)input_pos[b];
    float inv = powf(10000.f, -(float)tid * (1.f / 64.f));
    float ang = pos * inv;
    float c = cosf(ang), s = sinf(ang);
    float x1 = lds[tid], x2 = lds[tid + 64];
    float o1 = x1 * c - x2 * s;
    float o2 = x2 * c + x1 * s;
    float* dst = (kind == 0) ? (qf + (size_t)b * 4096 + hh * 128)
                             : (knew + (size_t)b * 1024 + (hh - 32) * 128);
    dst[tid] = o1;
    dst[tid + 64] = o2;
  }
}

// ---------------------------------------------------------------------------
// Kernel 3: paged GQA decode attention, KV-split, contiguous streaming.
// grid = B * ASPLIT = 512 blocks; 512 threads = 8 waves = 8 KV heads.
// Block (b, sp) streams positions [sp*128, sp*128+128) -> a CONTIGUOUS
// 512 KB region of each of kc/vc. No LDS, no barriers, no max-tracking
// (scores bounded: |q.k|*scale <= 11.4, exp <= 9e4, sums fit fp32 easily).
// Writes unnormalized partial (acc, ls) per (sp, b, head).
// ---------------------------------------------------------------------------
__global__ __launch_bounds__(512) void attn_decode(
    const float* __restrict__ qf, const float* __restrict__ knew,
    const float* __restrict__ vnew, const float* __restrict__ kc,
    const float* __restrict__ vc, const int* __restrict__ block_tables,
    const int* __restrict__ slot_mapping, const int* __restrict__ context_lens,
    float* __restrict__ pacc, float* __restrict__ pls) {
  const int b   = blockIdx.x >> 4;
  const int sp  = blockIdx.x & 15;
  const int tid = threadIdx.x;
  const int w   = tid >> 6;        // kv head 0..7
  const int lane = tid & 63;
  const int gi  = lane >> 4;       // group 0..3 (position within quad)
  const int l16 = lane & 15;
  const int d0  = l16 * 8;

  const int ctx   = context_lens[b];
  const int fslot = slot_mapping[b];
  const int base  = sp * APOS_;

  // one page covers this block's whole 128-position range (base % 128 == 0)
  const int page  = block_tables[b * NBPS_ + (base >> 8)];
  const int slot0 = (page << 8) + (base & 255);

  const float scale = 0.08838834764831845f;  // 1/sqrt(128)
  float q[4][8];
  #pragma unroll
  for (int g = 0; g < 4; ++g) {
    const float4* qp = (const float4*)(qf + ((size_t)b * H_ + w * G_ + g) * HD_ + d0);
    float4 a = qp[0], c = qp[1];
    q[g][0] = a.x * scale; q[g][1] = a.y * scale; q[g][2] = a.z * scale; q[g][3] = a.w * scale;
    q[g][4] = c.x * scale; q[g][5] = c.y * scale; q[g][6] = c.z * scale; q[g][7] = c.w * scale;
  }

  const float* knp = knew + ((size_t)b * HKV_ + w) * HD_ + d0;
  const float* vnp = vnew + ((size_t)b * HKV_ + w) * HD_ + d0;
  const float* kcb = kc + ((size_t)slot0 * HKV_ + w) * HD_ + d0;
  const float* vcb = vc + ((size_t)slot0 * HKV_ + w) * HD_ + d0;

  float ls[4] = {0.f, 0.f, 0.f, 0.f};
  float acc[4][8];
  #pragma unroll
  for (int g = 0; g < 4; ++g)
    #pragma unroll
    for (int j = 0; j < 8; ++j) acc[g][j] = 0.f;

  for (int it = 0; it < APOS_ / 4; ++it) {
    const int off = it * 4 + gi;           // 0..127
    const int pos = base + off;
    if (pos < ctx) {
      const int slot = slot0 + off;
      const float* kp = (slot == fslot) ? knp : (kcb + (size_t)off * (HKV_ * HD_));
      const float* vp = (slot == fslot) ? vnp : (vcb + (size_t)off * (HKV_ * HD_));
      float4 k1 = ((const float4*)kp)[0];
      float4 k2 = ((const float4*)kp)[1];
      float4 v1 = ((const float4*)vp)[0];
      float4 v2 = ((const float4*)vp)[1];
      float kk8[8] = {k1.x, k1.y, k1.z, k1.w, k2.x, k2.y, k2.z, k2.w};
      float vv[8]  = {v1.x, v1.y, v1.z, v1.w, v2.x, v2.y, v2.z, v2.w};

      float s[4];
      #pragma unroll
      for (int g = 0; g < 4; ++g) {
        float t = 0.f;
        #pragma unroll
        for (int j = 0; j < 8; ++j) t = fmaf(q[g][j], kk8[j], t);
        s[g] = t;
      }
      #pragma unroll
      for (int o2 = 1; o2 < 16; o2 <<= 1) {
        #pragma unroll
        for (int g = 0; g < 4; ++g) s[g] += __shfl_xor(s[g], o2);
      }
      #pragma unroll
      for (int g = 0; g < 4; ++g) {
        float pw = __expf(s[g]);
        ls[g] += pw;
        #pragma unroll
        for (int j = 0; j < 8; ++j) acc[g][j] = fmaf(pw, vv[j], acc[g][j]);
      }
    }
  }

  // sum the 4 position-groups within the wave (lanes differ only in gi)
  #pragma unroll
  for (int o2 = 16; o2 < 64; o2 <<= 1) {
    #pragma unroll
    for (int g = 0; g < 4; ++g) {
      ls[g] += __shfl_xor(ls[g], o2);
      #pragma unroll
      for (int j = 0; j < 8; ++j) acc[g][j] += __shfl_xor(acc[g][j], o2);
    }
  }

  if (gi == 0) {
    #pragma unroll
    for (int g = 0; g < 4; ++g) {
      float* dst = pacc + (((size_t)sp * B_ + b) * H_ + (w * G_ + g)) * HD_ + d0;
      float4 o1 = {acc[g][0], acc[g][1], acc[g][2], acc[g][3]};
      float4 o2 = {acc[g][4], acc[g][5], acc[g][6], acc[g][7]};
      ((float4*)dst)[0] = o1;
      ((float4*)dst)[1] = o2;
      if (l16 == 0) pls[((size_t)sp * B_ + b) * H_ + (w * G_ + g)] = ls[g];
    }
  }
}

// ---------------------------------------------------------------------------
// Kernel 3b: merge KV-split partials -> normalized attention output.
// 32768 float4 elements; grid = 128 x 256.
// ---------------------------------------------------------------------------
__global__ __launch_bounds__(256) void attn_merge(
    const float* __restrict__ pacc, const float* __restrict__ pls,
    float* __restrict__ attnb) {
  const int idx = blockIdx.x * 256 + threadIdx.x;  // float4 index, < 32768
  const int bh  = idx >> 5;                        // b*32 + h
  const float4* p4 = (const float4*)pacc;
  float4 A = {0.f, 0.f, 0.f, 0.f};
  float L = 0.f;
  #pragma unroll
  for (int sp = 0; sp < ASPLIT_; ++sp) {
    float4 t = p4[(size_t)sp * 32768 + idx];
    A.x += t.x; A.y += t.y; A.z += t.z; A.w += t.w;
    L += pls[sp * (B_ * H_) + bh];
  }
  float r = 1.f / L;
  A.x *= r; A.y *= r; A.z *= r; A.w *= r;
  ((float4*)attnb)[idx] = A;
}

// ---------------------------------------------------------------------------
// Kernel 4: output projection, split-K partials, register tiling (as kernel 1).
// grid = 16 n-tiles * 16 k-splits = 256 blocks, 256 threads.
// ---------------------------------------------------------------------------
__global__ __launch_bounds__(256) void oproj_gemm(
    const float* __restrict__ A, const float* __restrict__ Wo,
    float* __restrict__ P2) {
  const int tid = threadIdx.x;
  const int nid = blockIdx.x & 15;
  const int kid = blockIdx.x >> 4;
  const int k0 = kid * KC_;

  __shared__ __align__(16) float sT[KC_ * 36];
  #pragma unroll
  for (int m = 0; m < 32; ++m)
    sT[tid * 36 + m] = A[m * 4096 + k0 + tid];
  __syncthreads();

  const int ct = tid & 127;
  const int mh = tid >> 7;
  const int n  = nid * 256 + ct * 2;

  float2 acc[16];
  #pragma unroll
  for (int r = 0; r < 16; ++r) acc[r] = make_float2(0.f, 0.f);

  const float2* wp = (const float2*)(Wo + (size_t)k0 * 4096 + n);

  #pragma unroll 4
  for (int kk = 0; kk < KC_; ++kk) {
    float2 w = wp[(size_t)kk * 2048];
    const float4* s4 = (const float4*)(sT + kk * 36 + mh * 16);
    #pragma unroll
    for (int rq = 0; rq < 4; ++rq) {
      float4 a = s4[rq];
      acc[rq*4+0].x = fmaf(a.x, w.x, acc[rq*4+0].x);
      acc[rq*4+0].y = fmaf(a.x, w.y, acc[rq*4+0].y);
      acc[rq*4+1].x = fmaf(a.y, w.x, acc[rq*4+1].x);
      acc[rq*4+1].y = fmaf(a.y, w.y, acc[rq*4+1].y);
      acc[rq*4+2].x = fmaf(a.z, w.x, acc[rq*4+2].x);
      acc[rq*4+2].y = fmaf(a.z, w.y, acc[rq*4+2].y);
      acc[rq*4+3].x = fmaf(a.w, w.x, acc[rq*4+3].x);
      acc[rq*4+3].y = fmaf(a.w, w.y, acc[rq*4+3].y);
    }
  }

  float* o = P2 + (size_t)kid * 32 * 4096 + n;
  #pragma unroll
  for (int r = 0; r < 16; ++r) {
    int m = mh * 16 + r;
    *(float2*)(o + (size_t)m * 4096) = acc[r];
  }
}

// ---------------------------------------------------------------------------
// Kernel 5: reduce split-K partials of the output projection -> d_out.
// ---------------------------------------------------------------------------
__global__ __launch_bounds__(256) void oproj_reduce(
    const float* __restrict__ P2, float* __restrict__ out) {
  const int idx = blockIdx.x * 256 + threadIdx.x;  // < 131072
  float s = 0.f;
  #pragma unroll
  for (int t = 0; t < KSPLIT_; ++t) s += P2[(size_t)t * 131072 + idx];
  out[idx] = s;
}

// ---------------------------------------------------------------------------
extern "C" void kernel_launch(void* const* d_in, const int* in_sizes, int n_in,
                              void* d_out, int out_size, void* d_ws, size_t ws_size,
                              hipStream_t stream) {
  const float* seqs = (const float*)d_in[0];
  const float* Wq   = (const float*)d_in[1];
  const float* Wk   = (const float*)d_in[2];
  const float* Wv   = (const float*)d_in[3];
  const float* Wo   = (const float*)d_in[4];
  const float* qn_w = (const float*)d_in[5];
  const float* kn_w = (const float*)d_in[6];
  const float* kc   = (const float*)d_in[7];
  const float* vc   = (const float*)d_in[8];
  const int* input_pos = (const int*)d_in[9];
  const int* slot_map  = (const int*)d_in[10];
  const int* btab      = (const int*)d_in[11];
  const int* ctx       = (const int*)d_in[12];
  float* out = (float*)d_out;

  char* w = (char*)d_ws;
  float* P1    = (float*)(w);                      // 16*32*6144*4 = 12,582,912
  float* qf    = (float*)(w + 12582912);           // 32*4096*4    =    524,288
  float* knew  = (float*)(w + 13107200);           // 32*1024*4    =    131,072
  float* vnew  = (float*)(w + 13238272);           // 32*1024*4    =    131,072
  float* attnb = (float*)(w + 13369344);           // 32*4096*4    =    524,288
  float* pacc  = (float*)(w + 13893632);           // 16*32*32*128*4 = 8,388,608
  float* pls   = (float*)(w + 22282240);           // 16*32*32*4   =     65,536
  float* P2    = (float*)(w + 22347776);           // 16*32*4096*4 =  8,388,608

  qkv_gemm<<<24 * KSPLIT_, 256, 0, stream>>>(seqs, Wq, Wk, Wv, P1);
  reduce_norm_rope<<<B_ * 48, 128, 0, stream>>>(P1, qn_w, kn_w, input_pos, qf, knew, vnew);
  attn_decode<<<B_ * ASPLIT_, 512, 0, stream>>>(qf, knew, vnew, kc, vc, btab, slot_map, ctx, pacc, pls);
  attn_merge<<<128, 256, 0, stream>>>(pacc, pls, attnb);
  oproj_gemm<<<16 * KSPLIT_, 256, 0, stream>>>(attnb, Wo, P2);
  oproj_reduce<<<512, 256, 0, stream>>>(P2, out);
}

// Round 4
// 205.026 us; speedup vs baseline: 1.1128x; 1.0329x over previous
//
#include <hip/hip_runtime.h>
#include <hip/hip_bf16.h>
#include <math.h>

// Problem constants
#define B_     32
#define DM_    4096
#define H_     32
#define HKV_   8
#define G_     4
#define HD_    128
#define KVLEN_ 2048
#define NBPS_  8
#define NQKV_  6144   // 4096 q + 1024 k + 1024 v
#define KSPLIT_ 16
#define KC_    256    // 4096 / KSPLIT
#define ASPLIT_ 16
#define APOS_  128    // positions per attention block

typedef float vf4 __attribute__((ext_vector_type(4)));
typedef float vf2 __attribute__((ext_vector_type(2)));

// ---------------------------------------------------------------------------
// Kernel 0: transpose [32][4096] -> [4096][32]. grid = 64 blocks, 256 thr.
// ---------------------------------------------------------------------------
__global__ __launch_bounds__(256) void transpose32(
    const float* __restrict__ in, float* __restrict__ out) {
  __shared__ float t[32][65];
  const int tid = threadIdx.x;
  const int k0 = blockIdx.x * 64;
  #pragma unroll
  for (int it = 0; it < 8; ++it) {
    int m = it * 4 + (tid >> 6);
    int k = tid & 63;
    t[m][k] = in[(size_t)m * DM_ + k0 + k];
  }
  __syncthreads();
  #pragma unroll
  for (int it = 0; it < 8; ++it) {
    int flat = it * 256 + tid;
    out[(size_t)k0 * 32 + flat] = t[flat & 31][flat >> 5];
  }
}

// ---------------------------------------------------------------------------
// Kernel 1: fused QKV projection, split-K partials, NO LDS.
// A-operand read via wave-uniform address from seqsT (scalar-load friendly).
// grid = 24 n-tiles * 16 k-splits = 384 blocks, 256 threads.
// ---------------------------------------------------------------------------
__global__ __launch_bounds__(256) void qkv_gemm(
    const float* __restrict__ seqsT, const float* __restrict__ Wq,
    const float* __restrict__ Wk, const float* __restrict__ Wv,
    float* __restrict__ P1) {
  const int tid = threadIdx.x;
  const int nid = blockIdx.x % 24;
  const int kid = blockIdx.x / 24;
  const int k0 = kid * KC_;

  const int ct = tid & 127;
  const int mh16 = __builtin_amdgcn_readfirstlane((tid >> 7) << 4);  // 0 or 16
  const int n  = nid * 256 + ct * 2;

  const float* W; int col, ldw;
  if (nid < 16)      { W = Wq; col = n;        ldw = 4096; }
  else if (nid < 20) { W = Wk; col = n - 4096; ldw = 1024; }
  else               { W = Wv; col = n - 5120; ldw = 1024; }

  float2 acc[16];
  #pragma unroll
  for (int r = 0; r < 16; ++r) acc[r] = make_float2(0.f, 0.f);

  const vf2* wp = (const vf2*)(W + (size_t)k0 * ldw + col);
  const int ldw2 = ldw >> 1;
  const vf4* ap = (const vf4*)(seqsT + (size_t)k0 * 32 + mh16);

  #pragma unroll 8
  for (int kk = 0; kk < KC_; ++kk) {
    vf2 w = __builtin_nontemporal_load(wp + (size_t)kk * ldw2);
    vf4 a0 = ap[kk * 8 + 0];
    vf4 a1 = ap[kk * 8 + 1];
    vf4 a2 = ap[kk * 8 + 2];
    vf4 a3 = ap[kk * 8 + 3];
    #define FMA2(av, r) \
      acc[r].x = fmaf(av, w.x, acc[r].x); acc[r].y = fmaf(av, w.y, acc[r].y);
    FMA2(a0.x, 0)  FMA2(a0.y, 1)  FMA2(a0.z, 2)  FMA2(a0.w, 3)
    FMA2(a1.x, 4)  FMA2(a1.y, 5)  FMA2(a1.z, 6)  FMA2(a1.w, 7)
    FMA2(a2.x, 8)  FMA2(a2.y, 9)  FMA2(a2.z, 10) FMA2(a2.w, 11)
    FMA2(a3.x, 12) FMA2(a3.y, 13) FMA2(a3.z, 14) FMA2(a3.w, 15)
    #undef FMA2
  }

  float* o = P1 + (size_t)kid * 32 * NQKV_ + n;
  #pragma unroll
  for (int r = 0; r < 16; ++r) {
    int m = mh16 + r;
    *(float2*)(o + (size_t)m * NQKV_) = acc[r];
  }
}

// ---------------------------------------------------------------------------
// Kernel 2: reduce split-K partials, RMSNorm (q,k), RoPE (q,k).
// grid = 32 batches * 48 heads, 128 threads = HD.
// ---------------------------------------------------------------------------
__global__ __launch_bounds__(128) void reduce_norm_rope(
    const float* __restrict__ P1, const float* __restrict__ qn_w,
    const float* __restrict__ kn_w, const int* __restrict__ input_pos,
    float* __restrict__ qf, float* __restrict__ knew, float* __restrict__ vnew) {
  const int b = blockIdx.x / 48;
  const int hh = blockIdx.x % 48;
  const int tid = threadIdx.x;

  int col0, kind;  // 0=q,1=k,2=v
  if (hh < 32)      { kind = 0; col0 = hh * 128; }
  else if (hh < 40) { kind = 1; col0 = 4096 + (hh - 32) * 128; }
  else              { kind = 2; col0 = 5120 + (hh - 40) * 128; }

  float x = 0.f;
  const float* p = P1 + (size_t)b * NQKV_ + col0 + tid;
  #pragma unroll
  for (int s = 0; s < KSPLIT_; ++s) x += p[(size_t)s * 32 * NQKV_];

  if (kind == 2) {
    vnew[(size_t)b * 1024 + (hh - 40) * 128 + tid] = x;
    return;
  }

  __shared__ float lds[128];
  __shared__ float wred[2];
  float ss = x * x;
  #pragma unroll
  for (int off = 32; off > 0; off >>= 1) ss += __shfl_down(ss, off);
  if ((tid & 63) == 0) wred[tid >> 6] = ss;
  __syncthreads();
  float tot = wred[0] + wred[1];
  float r = rsqrtf(tot * (1.f / 128.f) + 1e-6f);
  const float* wv = (kind == 0) ? qn_w : kn_w;
  x = x * r * wv[tid];

  lds[tid] = x;
  __syncthreads();

  if (tid < 64) {
    float pos = (float)input_pos[b];
    float inv = powf(10000.f, -(float)tid * (1.f / 64.f));
    float ang = pos * inv;
    float c = cosf(ang), s = sinf(ang);
    float x1 = lds[tid], x2 = lds[tid + 64];
    float o1 = x1 * c - x2 * s;
    float o2 = x2 * c + x1 * s;
    float* dst = (kind == 0) ? (qf + (size_t)b * 4096 + hh * 128)
                             : (knew + (size_t)b * 1024 + (hh - 32) * 128);
    dst[tid] = o1;
    dst[tid + 64] = o2;
  }
}

// ---------------------------------------------------------------------------
// Kernel 3: paged GQA decode attention, KV-split, contiguous streaming.
// grid = B * ASPLIT = 512 blocks; 512 threads = 8 waves = 8 KV heads.
// Scores bounded (|q.k|*scale <= ~11.4) -> no max tracking needed.
// ---------------------------------------------------------------------------
__global__ __launch_bounds__(512) void attn_decode(
    const float* __restrict__ qf, const float* __restrict__ knew,
    const float* __restrict__ vnew, const float* __restrict__ kc,
    const float* __restrict__ vc, const int* __restrict__ block_tables,
    const int* __restrict__ slot_mapping, const int* __restrict__ context_lens,
    float* __restrict__ pacc, float* __restrict__ pls) {
  const int b   = blockIdx.x >> 4;
  const int sp  = blockIdx.x & 15;
  const int tid = threadIdx.x;
  const int w   = tid >> 6;        // kv head 0..7
  const int lane = tid & 63;
  const int gi  = lane >> 4;       // position-in-quad 0..3
  const int l16 = lane & 15;
  const int d0  = l16 * 8;

  const int ctx   = context_lens[b];
  const int fslot = slot_mapping[b];
  const int base  = sp * APOS_;

  const int page  = block_tables[b * NBPS_ + (base >> 8)];
  const int slot0 = (page << 8) + (base & 255);
  const int rel   = fslot - slot0;
  const bool hasf = (rel >= 0) && (rel < APOS_);
  const int nv    = min(APOS_, ctx - base);

  const float scale = 0.08838834764831845f;  // 1/sqrt(128)
  float q[4][8];
  #pragma unroll
  for (int g = 0; g < 4; ++g) {
    const float4* qp = (const float4*)(qf + ((size_t)b * H_ + w * G_ + g) * HD_ + d0);
    float4 a = qp[0], c = qp[1];
    q[g][0] = a.x * scale; q[g][1] = a.y * scale; q[g][2] = a.z * scale; q[g][3] = a.w * scale;
    q[g][4] = c.x * scale; q[g][5] = c.y * scale; q[g][6] = c.z * scale; q[g][7] = c.w * scale;
  }

  const float* knp = knew + ((size_t)b * HKV_ + w) * HD_ + d0;
  const float* vnp = vnew + ((size_t)b * HKV_ + w) * HD_ + d0;
  const float* kcb = kc + ((size_t)slot0 * HKV_ + w) * HD_ + d0;
  const float* vcb = vc + ((size_t)slot0 * HKV_ + w) * HD_ + d0;

  float ls[4] = {0.f, 0.f, 0.f, 0.f};
  float acc[4][8];
  #pragma unroll
  for (int g = 0; g < 4; ++g)
    #pragma unroll
    for (int j = 0; j < 8; ++j) acc[g][j] = 0.f;

  #define ATTN_STEP(K1, K2, V1, V2)                                       \
    {                                                                     \
      float kk8[8] = {K1.x, K1.y, K1.z, K1.w, K2.x, K2.y, K2.z, K2.w};    \
      float vv[8]  = {V1.x, V1.y, V1.z, V1.w, V2.x, V2.y, V2.z, V2.w};    \
      float s[4];                                                         \
      _Pragma("unroll")                                                   \
      for (int g = 0; g < 4; ++g) {                                       \
        float t = 0.f;                                                    \
        _Pragma("unroll")                                                 \
        for (int j = 0; j < 8; ++j) t = fmaf(q[g][j], kk8[j], t);         \
        s[g] = t;                                                         \
      }                                                                   \
      _Pragma("unroll")                                                   \
      for (int o2 = 1; o2 < 16; o2 <<= 1) {                               \
        _Pragma("unroll")                                                 \
        for (int g = 0; g < 4; ++g) s[g] += __shfl_xor(s[g], o2);         \
      }                                                                   \
      _Pragma("unroll")                                                   \
      for (int g = 0; g < 4; ++g) {                                       \
        float pw = __expf(s[g]);                                          \
        ls[g] += pw;                                                      \
        _Pragma("unroll")                                                 \
        for (int j = 0; j < 8; ++j) acc[g][j] = fmaf(pw, vv[j], acc[g][j]); \
      }                                                                   \
    }

  if (!hasf && nv == APOS_) {
    // fast path: pure contiguous stream, no fresh slot, all positions valid
    #pragma unroll 2
    for (int it = 0; it < APOS_ / 4; ++it) {
      const int off = it * 4 + gi;
      const vf4* kp4 = (const vf4*)(kcb + (size_t)off * (HKV_ * HD_));
      const vf4* vp4 = (const vf4*)(vcb + (size_t)off * (HKV_ * HD_));
      vf4 k1 = __builtin_nontemporal_load(kp4);
      vf4 k2 = __builtin_nontemporal_load(kp4 + 1);
      vf4 v1 = __builtin_nontemporal_load(vp4);
      vf4 v2 = __builtin_nontemporal_load(vp4 + 1);
      ATTN_STEP(k1, k2, v1, v2)
    }
  } else {
    for (int it = 0; it < APOS_ / 4; ++it) {
      const int off = it * 4 + gi;
      if (base + off < ctx) {
        const float* kp = (off == rel) ? knp : (kcb + (size_t)off * (HKV_ * HD_));
        const float* vp = (off == rel) ? vnp : (vcb + (size_t)off * (HKV_ * HD_));
        float4 k1 = ((const float4*)kp)[0];
        float4 k2 = ((const float4*)kp)[1];
        float4 v1 = ((const float4*)vp)[0];
        float4 v2 = ((const float4*)vp)[1];
        ATTN_STEP(k1, k2, v1, v2)
      }
    }
  }
  #undef ATTN_STEP

  // sum the 4 position-groups within the wave
  #pragma unroll
  for (int o2 = 16; o2 < 64; o2 <<= 1) {
    #pragma unroll
    for (int g = 0; g < 4; ++g) {
      ls[g] += __shfl_xor(ls[g], o2);
      #pragma unroll
      for (int j = 0; j < 8; ++j) acc[g][j] += __shfl_xor(acc[g][j], o2);
    }
  }

  if (gi == 0) {
    #pragma unroll
    for (int g = 0; g < 4; ++g) {
      float* dst = pacc + (((size_t)sp * B_ + b) * H_ + (w * G_ + g)) * HD_ + d0;
      float4 o1 = {acc[g][0], acc[g][1], acc[g][2], acc[g][3]};
      float4 o2 = {acc[g][4], acc[g][5], acc[g][6], acc[g][7]};
      ((float4*)dst)[0] = o1;
      ((float4*)dst)[1] = o2;
      if (l16 == 0) pls[((size_t)sp * B_ + b) * H_ + (w * G_ + g)] = ls[g];
    }
  }
}

// ---------------------------------------------------------------------------
// Kernel 3b: merge KV-split partials -> normalized attention output [32][4096].
// ---------------------------------------------------------------------------
__global__ __launch_bounds__(256) void attn_merge(
    const float* __restrict__ pacc, const float* __restrict__ pls,
    float* __restrict__ attnb) {
  const int idx = blockIdx.x * 256 + threadIdx.x;  // float4 index, < 32768
  const int bh  = idx >> 5;                        // b*32 + h
  const float4* p4 = (const float4*)pacc;
  float4 A = {0.f, 0.f, 0.f, 0.f};
  float L = 0.f;
  #pragma unroll
  for (int sp = 0; sp < ASPLIT_; ++sp) {
    float4 t = p4[(size_t)sp * 32768 + idx];
    A.x += t.x; A.y += t.y; A.z += t.z; A.w += t.w;
    L += pls[sp * (B_ * H_) + bh];
  }
  float r = 1.f / L;
  A.x *= r; A.y *= r; A.z *= r; A.w *= r;
  ((float4*)attnb)[idx] = A;
}

// ---------------------------------------------------------------------------
// Kernel 4: output projection, split-K partials, NO LDS (A from attnT).
// grid = 16 n-tiles * 16 k-splits = 256 blocks, 512 threads.
// ---------------------------------------------------------------------------
__global__ __launch_bounds__(512) void oproj_gemm(
    const float* __restrict__ attnT, const float* __restrict__ Wo,
    float* __restrict__ P2) {
  const int tid = threadIdx.x;
  const int nid = blockIdx.x & 15;
  const int kid = blockIdx.x >> 4;
  const int k0 = kid * KC_;

  const int ct = tid & 127;
  const int mq8 = __builtin_amdgcn_readfirstlane((tid >> 7) << 3);  // 0,8,16,24
  const int n  = nid * 256 + ct * 2;

  float2 acc[8];
  #pragma unroll
  for (int r = 0; r < 8; ++r) acc[r] = make_float2(0.f, 0.f);

  const vf2* wp = (const vf2*)(Wo + (size_t)k0 * 4096 + n);
  const vf4* ap = (const vf4*)(attnT + (size_t)k0 * 32 + mq8);

  #pragma unroll 8
  for (int kk = 0; kk < KC_; ++kk) {
    vf2 w = __builtin_nontemporal_load(wp + (size_t)kk * 2048);
    vf4 a0 = ap[kk * 8 + 0];
    vf4 a1 = ap[kk * 8 + 1];
    #define FMA2(av, r) \
      acc[r].x = fmaf(av, w.x, acc[r].x); acc[r].y = fmaf(av, w.y, acc[r].y);
    FMA2(a0.x, 0) FMA2(a0.y, 1) FMA2(a0.z, 2) FMA2(a0.w, 3)
    FMA2(a1.x, 4) FMA2(a1.y, 5) FMA2(a1.z, 6) FMA2(a1.w, 7)
    #undef FMA2
  }

  float* o = P2 + (size_t)kid * 32 * 4096 + n;
  #pragma unroll
  for (int r = 0; r < 8; ++r) {
    int m = mq8 + r;
    *(float2*)(o + (size_t)m * 4096) = acc[r];
  }
}

// ---------------------------------------------------------------------------
// Kernel 5: reduce split-K partials of the output projection -> d_out.
// ---------------------------------------------------------------------------
__global__ __launch_bounds__(256) void oproj_reduce(
    const float* __restrict__ P2, float* __restrict__ out) {
  const int idx = blockIdx.x * 256 + threadIdx.x;  // < 131072
  float s = 0.f;
  #pragma unroll
  for (int t = 0; t < KSPLIT_; ++t) s += P2[(size_t)t * 131072 + idx];
  out[idx] = s;
}

// ---------------------------------------------------------------------------
extern "C" void kernel_launch(void* const* d_in, const int* in_sizes, int n_in,
                              void* d_out, int out_size, void* d_ws, size_t ws_size,
                              hipStream_t stream) {
  const float* seqs = (const float*)d_in[0];
  const float* Wq   = (const float*)d_in[1];
  const float* Wk   = (const float*)d_in[2];
  const float* Wv   = (const float*)d_in[3];
  const float* Wo   = (const float*)d_in[4];
  const float* qn_w = (const float*)d_in[5];
  const float* kn_w = (const float*)d_in[6];
  const float* kc   = (const float*)d_in[7];
  const float* vc   = (const float*)d_in[8];
  const int* input_pos = (const int*)d_in[9];
  const int* slot_map  = (const int*)d_in[10];
  const int* btab      = (const int*)d_in[11];
  const int* ctx       = (const int*)d_in[12];
  float* out = (float*)d_out;

  char* w = (char*)d_ws;
  float* seqsT = (float*)(w);                    // 512 KB
  float* P1    = (float*)(w + 1048576);          // 12,582,912
  float* qf    = (float*)(w + 14680064);         // 524,288
  float* knew  = (float*)(w + 15204352);         // 131,072
  float* vnew  = (float*)(w + 15335424);         // 131,072
  float* attnb = (float*)(w + 15466496);         // 524,288
  float* attnT = (float*)(w + 15990784);         // 524,288
  float* pacc  = (float*)(w + 16515072);         // 8,388,608
  float* pls   = (float*)(w + 24903680);         // 65,536
  float* P2    = (float*)(w + 24969216);         // 8,388,608

  transpose32<<<64, 256, 0, stream>>>(seqs, seqsT);
  qkv_gemm<<<24 * KSPLIT_, 256, 0, stream>>>(seqsT, Wq, Wk, Wv, P1);
  reduce_norm_rope<<<B_ * 48, 128, 0, stream>>>(P1, qn_w, kn_w, input_pos, qf, knew, vnew);
  attn_decode<<<B_ * ASPLIT_, 512, 0, stream>>>(qf, knew, vnew, kc, vc, btab, slot_map, ctx, pacc, pls);
  attn_merge<<<128, 256, 0, stream>>>(pacc, pls, attnb);
  transpose32<<<64, 256, 0, stream>>>(attnb, attnT);
  oproj_gemm<<<16 * KSPLIT_, 512, 0, stream>>>(attnT, Wo, P2);
  oproj_reduce<<<512, 256, 0, stream>>>(P2, out);
}